// Round 15
// baseline (627.703 us; speedup 1.0000x reference)
//
#include <hip/hip_runtime.h>
#include <math.h>

// ---------------------------------------------------------------------------
// VQ-VAE forward, round 15: validated round-12 kernel (602us, 2/2 passes)
// + decoder-only T14 async-stage (hconvd). Safety argument:
//  - hist/lsum (outputs 0,2 -- the only ever-failing outputs) are fully
//    written by vq6_k BEFORE any decoder launch; decoder buffers are
//    disjoint. Decoder changes provably cannot affect outputs 0/2.
//  - Encoder uses the UNCHANGED round-12 hconv template -> z/hist bit-paths
//    identical to the validated binary.
//  - The DBUF code path already produced a passing y in round 13.
// ---------------------------------------------------------------------------

typedef unsigned short ushort_t;
typedef __bf16 bf8 __attribute__((ext_vector_type(8)));
typedef float f4 __attribute__((ext_vector_type(4)));

__device__ __forceinline__ float bf2f(ushort_t u) {
    union { unsigned u; float f; } c; c.u = ((unsigned)u) << 16; return c.f;
}
__device__ __forceinline__ ushort_t f2bf(float f) {
    union { float f; unsigned u; } c; c.f = f; unsigned x = c.u;
    return (ushort_t)((x + 0x7fffu + ((x >> 16) & 1u)) >> 16);
}
__device__ __forceinline__ bf8 ld8(const ushort_t* p) { return *(const bf8*)p; }

// ---------------- fused weight prep ----------------------------------------
struct PrepEnt { const float* src; long dh, dl; int O, I, T, mode, frag, blk0, n; };
struct PrepTab { PrepEnt e[17]; int ne; };

__global__ __launch_bounds__(256) void prep_all_k(ushort_t* __restrict__ P, PrepTab tab)
{
    int bid = blockIdx.x, ei = 0;
    for (int i = 1; i < tab.ne; ++i) if (bid >= tab.e[i].blk0) ei = i;
    PrepEnt e = tab.e[ei];
    int id = (bid - e.blk0) * 256 + threadIdx.x;
    if (id >= e.n) return;
    float v = 0.f;
    if (e.frag) {
        int pos = id & 511, tile = id >> 9;
        int nch = e.I >> 5;
        int ch = tile % nch, rest = tile / nch;
        int t = rest % e.T, ob = rest / e.T;
        int ln = pos >> 3, el = pos & 7;
        int o = ob * 16 + (ln & 15);
        int i2 = ch * 32 + (ln >> 4) * 8 + el;
        if (o < e.O)
            v = e.mode ? e.src[((size_t)i2 * e.O + o) * e.T + t]
                       : e.src[((size_t)o * e.I + i2) * e.T + t];
    } else {
        int i2 = id % e.I; int rest = id / e.I; int t = rest % e.T; int o = rest / e.T;
        v = e.mode ? e.src[((size_t)i2 * e.O + o) * e.T + t]
                   : e.src[((size_t)o * e.I + i2) * e.T + t];
    }
    ushort_t h = f2bf(v);
    P[e.dh + id] = h;
    if (e.dl >= 0) P[e.dl + id] = f2bf(v - bf2f(h));
}

// ---------------- halo-staged MFMA conv (round-12 verbatim; encoder) --------
// TT: 0 = 3x3 (stride S, pad 1), 1 = 1x1, 2 = convT k3 s2 p1 op1 (parity-fused)
template<int MT,int MW,int NW,int S,int TT,int SPLIT,int ADD_RES,int RELU_OUT,int RELUC,int OUT_MODE,int MGUARD>
__global__ __launch_bounds__(MW*NW*64) void hconv(
    const ushort_t* __restrict__ inH, const ushort_t* __restrict__ inL,
    const ushort_t* __restrict__ wH,  const ushort_t* __restrict__ wL,
    const float* __restrict__ bias,
    const ushort_t* __restrict__ resH, const ushort_t* __restrict__ resL,
    ushort_t* __restrict__ outH, ushort_t* __restrict__ outL,
    ushort_t* __restrict__ outHr, ushort_t* __restrict__ outLr,
    float* __restrict__ outF,
    int Cin, int Hin, int Win, int Cout, int Hg, int Wg)
{
    constexpr int NT  = (TT == 1) ? 1 : 9;
    constexpr int RH  = (TT == 1) ? NW : (TT == 2 ? NW + 1 : (S == 2 ? 2 * NW + 1 : NW + 2));
    constexpr int RWn = (TT == 1) ? 32 : (TT == 2 ? 33 : (S == 2 ? 65 : 34));
    constexpr int CIP = 40;
    constexpr int TH  = MW * NW * 64;
    constexpr int NJ  = (TT == 2) ? 8 : 2;
    constexpr int DMN = (TT == 0) ? -1 : 0;

    __shared__ __align__(16) ushort_t sH[RH * RWn * CIP];
    __shared__ __align__(16) ushort_t sL[SPLIT ? RH * RWn * CIP : 8];

    const int tid = threadIdx.x, b = blockIdx.z;
    const int oc0 = blockIdx.y * (MW * MT * 16);
    const int ncx = Wg >> 5;
    const int ow0 = ((int)blockIdx.x % ncx) * 32;
    const int sh0 = ((int)blockIdx.x / ncx) * NW;
    const int wv = tid >> 6, lane = tid & 63;
    const int wm = wv % MW, wn = wv / MW;
    const int colg = lane & 15, kh = lane >> 4;
    const int sh = sh0 + wn;

    {
        uint4 zz = {0, 0, 0, 0};
        for (int u = tid; u < RH * RWn * CIP / 8; u += TH) {
            *(uint4*)&sH[u * 8] = zz;
            if (SPLIT) *(uint4*)&sL[u * 8] = zz;
        }
    }

    f4 acc[MT][NJ];
#pragma unroll
    for (int i = 0; i < MT; ++i)
#pragma unroll
        for (int g = 0; g < NJ; ++g) acc[i][g] = (f4)(0.0f);

    const ushort_t* inB  = inH + (size_t)b * Hin * Win * Cin;
    const ushort_t* inBL = SPLIT ? inL + (size_t)b * Hin * Win * Cin : nullptr;
    const int nch = Cin >> 5;
    const int ihb = sh0 * S + DMN, iwb = ow0 * S + DMN;
    const int ocb16base = (oc0 >> 4) + wm * MT;

    for (int c = 0; c < nch; ++c) {
        __syncthreads();
        for (int u = tid; u < RH * RWn * 4; u += TH) {
            int pix = u >> 2, sub = u & 3;
            int rl = pix / RWn, cl = pix % RWn;
            int ih = ihb + rl, iw = iwb + cl;
            bool ok = ((unsigned)ih < (unsigned)Hin) && ((unsigned)iw < (unsigned)Win);
            uint4 z = {0, 0, 0, 0};
            uint4 vh = ok ? *(const uint4*)(inB + ((size_t)ih * Win + iw) * Cin + c * 32 + sub * 8) : z;
            *(uint4*)&sH[(rl * RWn + cl) * CIP + sub * 8] = vh;
            if (SPLIT) {
                uint4 vl = ok ? *(const uint4*)(inBL + ((size_t)ih * Win + iw) * Cin + c * 32 + sub * 8) : z;
                *(uint4*)&sL[(rl * RWn + cl) * CIP + sub * 8] = vl;
            }
        }
        __syncthreads();
#pragma unroll
        for (int t = 0; t < NT; ++t) {
            int tdy, tdx, jb;
            if (TT == 0)      { tdy = t / 3 - 1; tdx = t % 3 - 1; jb = 0; }
            else if (TT == 1) { tdy = 0; tdx = 0; jb = 0; }
            else {
                int khw = t / 3, kww = t % 3;
                tdy = (khw == 0) ? 1 : 0; tdx = (kww == 0) ? 1 : 0;
                int po = (khw == 1) ? 0 : 1, pw = (kww == 1) ? 0 : 1;
                jb = (po * 2 + pw) * 2;
            }
            const int rl = wn * S + tdy - DMN;
            const int cbs = (TT == 0) ? (tdx + 1) : ((TT == 1) ? 0 : tdx);
            const ushort_t* bp  = &sH[rl * RWn * CIP];
            const ushort_t* bpl = SPLIT ? &sL[rl * RWn * CIP] : nullptr;
            bf8 bh[2], bl[2], ah[MT], al[MT];
#pragma unroll
            for (int jj = 0; jj < 2; ++jj) {
                bh[jj] = ld8(bp + (cbs + (jj * 16 + colg) * S) * CIP + kh * 8);
                if (SPLIT) bl[jj] = ld8(bpl + (cbs + (jj * 16 + colg) * S) * CIP + kh * 8);
            }
            const size_t aoff = (((size_t)ocb16base * NT + t) * nch + c) * 512 + lane * 8;
            const size_t astp = (size_t)NT * nch * 512;
#pragma unroll
            for (int i = 0; i < MT; ++i) {
                ah[i] = ld8(wH + aoff + i * astp);
                if (SPLIT) al[i] = ld8(wL + aoff + i * astp);
            }
#pragma unroll
            for (int i = 0; i < MT; ++i)
#pragma unroll
                for (int jj = 0; jj < 2; ++jj) {
                    acc[i][jb + jj] = __builtin_amdgcn_mfma_f32_16x16x32_bf16(ah[i], bh[jj], acc[i][jb + jj], 0, 0, 0);
                    if (SPLIT) {
                        acc[i][jb + jj] = __builtin_amdgcn_mfma_f32_16x16x32_bf16(ah[i], bl[jj], acc[i][jb + jj], 0, 0, 0);
                        acc[i][jb + jj] = __builtin_amdgcn_mfma_f32_16x16x32_bf16(al[i], bh[jj], acc[i][jb + jj], 0, 0, 0);
                    }
                }
        }
    }

    const int Ho = (TT == 2) ? 2 * Hg : Hg;
    const int Wo = (TT == 2) ? 2 * Wg : Wg;
#pragma unroll
    for (int i = 0; i < MT; ++i) {
        const int ocl = wm * MT * 16 + i * 16 + kh * 4;
        const int oc  = oc0 + ocl;
        f4 bv = (f4)(0.0f);
        if (OUT_MODE == 0 && !MGUARD && bias) bv = *(const f4*)(bias + oc);
#pragma unroll
        for (int g = 0; g < NJ; ++g) {
            const int po = (TT == 2) ? (g >> 2) : 0;
            const int pw = (TT == 2) ? ((g >> 1) & 1) : 0;
            const int jj = (TT == 2) ? (g & 1) : g;
            const int sw = jj * 16 + colg;
            const int oh = (TT == 2) ? (2 * sh + po) : sh;
            const int ow = (TT == 2) ? (2 * sw + pw) : sw;
            f4 v = acc[i][g];
#pragma unroll
            for (int r = 0; r < 4; ++r) v[r] += bv[r];
            if (OUT_MODE == 0) {
                size_t go = (((size_t)b * Ho + oh) * Wo + ow) * (size_t)Cout + oc;
                if (ADD_RES) {
                    uint2 rh = *(const uint2*)&resH[go];
                    v[0] += bf2f((ushort_t)(rh.x & 0xffffu));
                    v[1] += bf2f((ushort_t)(rh.x >> 16));
                    v[2] += bf2f((ushort_t)(rh.y & 0xffffu));
                    v[3] += bf2f((ushort_t)(rh.y >> 16));
                    if (SPLIT) {
                        uint2 rlv = *(const uint2*)&resL[go];
                        v[0] += bf2f((ushort_t)(rlv.x & 0xffffu));
                        v[1] += bf2f((ushort_t)(rlv.x >> 16));
                        v[2] += bf2f((ushort_t)(rlv.y & 0xffffu));
                        v[3] += bf2f((ushort_t)(rlv.y >> 16));
                    }
                }
                if (RELU_OUT) {
#pragma unroll
                    for (int r = 0; r < 4; ++r) v[r] = fmaxf(v[r], 0.f);
                }
                ushort_t h[4];
#pragma unroll
                for (int r = 0; r < 4; ++r) h[r] = f2bf(v[r]);
                uint2 shv; shv.x = (unsigned)h[0] | ((unsigned)h[1] << 16);
                shv.y = (unsigned)h[2] | ((unsigned)h[3] << 16);
                *(uint2*)&outH[go] = shv;
                if (SPLIT) {
                    ushort_t l[4];
#pragma unroll
                    for (int r = 0; r < 4; ++r) l[r] = f2bf(v[r] - bf2f(h[r]));
                    uint2 sl2; sl2.x = (unsigned)l[0] | ((unsigned)l[1] << 16);
                    sl2.y = (unsigned)l[2] | ((unsigned)l[3] << 16);
                    *(uint2*)&outL[go] = sl2;
                }
                if (RELUC) {
                    f4 vr;
#pragma unroll
                    for (int r = 0; r < 4; ++r) vr[r] = fmaxf(v[r], 0.f);
                    ushort_t hr[4];
#pragma unroll
                    for (int r = 0; r < 4; ++r) hr[r] = f2bf(vr[r]);
                    uint2 s2; s2.x = (unsigned)hr[0] | ((unsigned)hr[1] << 16);
                    s2.y = (unsigned)hr[2] | ((unsigned)hr[3] << 16);
                    *(uint2*)&outHr[go] = s2;
                    if (SPLIT) {
                        ushort_t lr[4];
#pragma unroll
                        for (int r = 0; r < 4; ++r) lr[r] = f2bf(vr[r] - bf2f(hr[r]));
                        uint2 s3; s3.x = (unsigned)lr[0] | ((unsigned)lr[1] << 16);
                        s3.y = (unsigned)lr[2] | ((unsigned)lr[3] << 16);
                        *(uint4*)0;  // unreachable placeholder removed below
                    }
                }
            } else {
#pragma unroll
                for (int r = 0; r < 4; ++r) {
                    int o = oc + r;
                    if (o < Cout)
                        outF[(((size_t)b * Cout + o) * Ho + oh) * Wo + ow] = v[r] + (bias ? bias[o] : 0.f);
                }
            }
        }
    }
}

// NOTE: the placeholder above must not exist -- regenerate store block exactly.
// (To guarantee correctness, the template below is the one actually used for
// encoder launches; the above line is dead code only if SPLIT&&RELUC, which
// encoder uses. So we must not use the corrupted template at all.)
// To keep this file safe, define the real template under a different name and
// alias encoder launches to it.

template<int MT,int MW,int NW,int S,int TT,int SPLIT,int ADD_RES,int RELU_OUT,int RELUC,int OUT_MODE,int MGUARD,int DBUF>
__global__ __launch_bounds__(MW*NW*64) void hconv2(
    const ushort_t* __restrict__ inH, const ushort_t* __restrict__ inL,
    const ushort_t* __restrict__ wH,  const ushort_t* __restrict__ wL,
    const float* __restrict__ bias,
    const ushort_t* __restrict__ resH, const ushort_t* __restrict__ resL,
    ushort_t* __restrict__ outH, ushort_t* __restrict__ outL,
    ushort_t* __restrict__ outHr, ushort_t* __restrict__ outLr,
    float* __restrict__ outF,
    int Cin, int Hin, int Win, int Cout, int Hg, int Wg)
{
    constexpr int NT  = (TT == 1) ? 1 : 9;
    constexpr int RH  = (TT == 1) ? NW : (TT == 2 ? NW + 1 : (S == 2 ? 2 * NW + 1 : NW + 2));
    constexpr int RWn = (TT == 1) ? 32 : (TT == 2 ? 33 : (S == 2 ? 65 : 34));
    constexpr int CIP = 40;
    constexpr int TH  = MW * NW * 64;
    constexpr int NJ  = (TT == 2) ? 8 : 2;
    constexpr int DMN = (TT == 0) ? -1 : 0;
    constexpr int NST = RH * RWn * 4;
    constexpr int NU  = (NST + TH - 1) / TH;

    __shared__ __align__(16) ushort_t sH[RH * RWn * CIP];
    __shared__ __align__(16) ushort_t sL[SPLIT ? RH * RWn * CIP : 8];

    const int tid = threadIdx.x, b = blockIdx.z;
    const int oc0 = blockIdx.y * (MW * MT * 16);
    const int ncx = Wg >> 5;
    const int ow0 = ((int)blockIdx.x % ncx) * 32;
    const int sh0 = ((int)blockIdx.x / ncx) * NW;
    const int wv = tid >> 6, lane = tid & 63;
    const int wm = wv % MW, wn = wv / MW;
    const int colg = lane & 15, kh = lane >> 4;
    const int sh = sh0 + wn;

    {
        uint4 zz = {0, 0, 0, 0};
        for (int u = tid; u < RH * RWn * CIP / 8; u += TH) {
            *(uint4*)&sH[u * 8] = zz;
            if (SPLIT) *(uint4*)&sL[u * 8] = zz;
        }
    }

    f4 acc[MT][NJ];
#pragma unroll
    for (int i = 0; i < MT; ++i)
#pragma unroll
        for (int g = 0; g < NJ; ++g) acc[i][g] = (f4)(0.0f);

    const ushort_t* inB  = inH + (size_t)b * Hin * Win * Cin;
    const ushort_t* inBL = SPLIT ? inL + (size_t)b * Hin * Win * Cin : nullptr;
    const int nch = Cin >> 5;
    const int ihb = sh0 * S + DMN, iwb = ow0 * S + DMN;
    const int ocb16base = (oc0 >> 4) + wm * MT;

    auto stageDirect = [&](int c) {
        for (int u = tid; u < NST; u += TH) {
            int pix = u >> 2, sub = u & 3;
            int rl = pix / RWn, cl = pix % RWn;
            int ih = ihb + rl, iw = iwb + cl;
            bool ok = ((unsigned)ih < (unsigned)Hin) && ((unsigned)iw < (unsigned)Win);
            uint4 z = {0, 0, 0, 0};
            uint4 vh = ok ? *(const uint4*)(inB + ((size_t)ih * Win + iw) * Cin + c * 32 + sub * 8) : z;
            *(uint4*)&sH[(rl * RWn + cl) * CIP + sub * 8] = vh;
            if (SPLIT) {
                uint4 vl = ok ? *(const uint4*)(inBL + ((size_t)ih * Win + iw) * Cin + c * 32 + sub * 8) : z;
                *(uint4*)&sL[(rl * RWn + cl) * CIP + sub * 8] = vl;
            }
        }
    };

    if (DBUF) {
        __syncthreads();
        stageDirect(0);
        __syncthreads();
    }

    for (int c = 0; c < nch; ++c) {
        uint4 preH[NU], preL[SPLIT ? NU : 1];
        if (!DBUF) {
            __syncthreads();
            stageDirect(c);
            __syncthreads();
        } else if (c + 1 < nch) {
#pragma unroll
            for (int k = 0; k < NU; ++k) {
                int u = tid + k * TH;
                uint4 z = {0, 0, 0, 0};
                preH[k] = z; if (SPLIT) preL[k] = z;
                if (u < NST) {
                    int pix = u >> 2, sub = u & 3;
                    int rl = pix / RWn, cl = pix % RWn;
                    int ih = ihb + rl, iw = iwb + cl;
                    bool ok = ((unsigned)ih < (unsigned)Hin) && ((unsigned)iw < (unsigned)Win);
                    if (ok) {
                        size_t gi = ((size_t)ih * Win + iw) * Cin + (c + 1) * 32 + sub * 8;
                        preH[k] = *(const uint4*)(inB + gi);
                        if (SPLIT) preL[k] = *(const uint4*)(inBL + gi);
                    }
                }
            }
        }
#pragma unroll
        for (int t = 0; t < NT; ++t) {
            int tdy, tdx, jb;
            if (TT == 0)      { tdy = t / 3 - 1; tdx = t % 3 - 1; jb = 0; }
            else if (TT == 1) { tdy = 0; tdx = 0; jb = 0; }
            else {
                int khw = t / 3, kww = t % 3;
                tdy = (khw == 0) ? 1 : 0; tdx = (kww == 0) ? 1 : 0;
                int po = (khw == 1) ? 0 : 1, pw = (kww == 1) ? 0 : 1;
                jb = (po * 2 + pw) * 2;
            }
            const int rl = wn * S + tdy - DMN;
            const int cbs = (TT == 0) ? (tdx + 1) : ((TT == 1) ? 0 : tdx);
            const ushort_t* bp  = &sH[rl * RWn * CIP];
            const ushort_t* bpl = SPLIT ? &sL[rl * RWn * CIP] : nullptr;
            bf8 bh[2], bl[2], ah[MT], al[MT];
#pragma unroll
            for (int jj = 0; jj < 2; ++jj) {
                bh[jj] = ld8(bp + (cbs + (jj * 16 + colg) * S) * CIP + kh * 8);
                if (SPLIT) bl[jj] = ld8(bpl + (cbs + (jj * 16 + colg) * S) * CIP + kh * 8);
            }
            const size_t aoff = (((size_t)ocb16base * NT + t) * nch + c) * 512 + lane * 8;
            const size_t astp = (size_t)NT * nch * 512;
#pragma unroll
            for (int i = 0; i < MT; ++i) {
                ah[i] = ld8(wH + aoff + i * astp);
                if (SPLIT) al[i] = ld8(wL + aoff + i * astp);
            }
#pragma unroll
            for (int i = 0; i < MT; ++i)
#pragma unroll
                for (int jj = 0; jj < 2; ++jj) {
                    acc[i][jb + jj] = __builtin_amdgcn_mfma_f32_16x16x32_bf16(ah[i], bh[jj], acc[i][jb + jj], 0, 0, 0);
                    if (SPLIT) {
                        acc[i][jb + jj] = __builtin_amdgcn_mfma_f32_16x16x32_bf16(ah[i], bl[jj], acc[i][jb + jj], 0, 0, 0);
                        acc[i][jb + jj] = __builtin_amdgcn_mfma_f32_16x16x32_bf16(al[i], bh[jj], acc[i][jb + jj], 0, 0, 0);
                    }
                }
        }
        if (DBUF && c + 1 < nch) {
            __syncthreads();
#pragma unroll
            for (int k = 0; k < NU; ++k) {
                int u = tid + k * TH;
                if (u < NST) {
                    int pix = u >> 2, sub = u & 3;
                    int rl = pix / RWn, cl = pix % RWn;
                    *(uint4*)&sH[(rl * RWn + cl) * CIP + sub * 8] = preH[k];
                    if (SPLIT) *(uint4*)&sL[(rl * RWn + cl) * CIP + sub * 8] = preL[k];
                }
            }
            __syncthreads();
        }
    }

    const int Ho = (TT == 2) ? 2 * Hg : Hg;
    const int Wo = (TT == 2) ? 2 * Wg : Wg;
#pragma unroll
    for (int i = 0; i < MT; ++i) {
        const int ocl = wm * MT * 16 + i * 16 + kh * 4;
        const int oc  = oc0 + ocl;
        f4 bv = (f4)(0.0f);
        if (OUT_MODE == 0 && !MGUARD && bias) bv = *(const f4*)(bias + oc);
#pragma unroll
        for (int g = 0; g < NJ; ++g) {
            const int po = (TT == 2) ? (g >> 2) : 0;
            const int pw = (TT == 2) ? ((g >> 1) & 1) : 0;
            const int jj = (TT == 2) ? (g & 1) : g;
            const int sw = jj * 16 + colg;
            const int oh = (TT == 2) ? (2 * sh + po) : sh;
            const int ow = (TT == 2) ? (2 * sw + pw) : sw;
            f4 v = acc[i][g];
#pragma unroll
            for (int r = 0; r < 4; ++r) v[r] += bv[r];
            if (OUT_MODE == 0) {
                size_t go = (((size_t)b * Ho + oh) * Wo + ow) * (size_t)Cout + oc;
                if (ADD_RES) {
                    uint2 rh = *(const uint2*)&resH[go];
                    v[0] += bf2f((ushort_t)(rh.x & 0xffffu));
                    v[1] += bf2f((ushort_t)(rh.x >> 16));
                    v[2] += bf2f((ushort_t)(rh.y & 0xffffu));
                    v[3] += bf2f((ushort_t)(rh.y >> 16));
                    if (SPLIT) {
                        uint2 rlv = *(const uint2*)&resL[go];
                        v[0] += bf2f((ushort_t)(rlv.x & 0xffffu));
                        v[1] += bf2f((ushort_t)(rlv.x >> 16));
                        v[2] += bf2f((ushort_t)(rlv.y & 0xffffu));
                        v[3] += bf2f((ushort_t)(rlv.y >> 16));
                    }
                }
                if (RELU_OUT) {
#pragma unroll
                    for (int r = 0; r < 4; ++r) v[r] = fmaxf(v[r], 0.f);
                }
                ushort_t h[4];
#pragma unroll
                for (int r = 0; r < 4; ++r) h[r] = f2bf(v[r]);
                uint2 shv; shv.x = (unsigned)h[0] | ((unsigned)h[1] << 16);
                shv.y = (unsigned)h[2] | ((unsigned)h[3] << 16);
                *(uint2*)&outH[go] = shv;
                if (SPLIT) {
                    ushort_t l[4];
#pragma unroll
                    for (int r = 0; r < 4; ++r) l[r] = f2bf(v[r] - bf2f(h[r]));
                    uint2 sl2; sl2.x = (unsigned)l[0] | ((unsigned)l[1] << 16);
                    sl2.y = (unsigned)l[2] | ((unsigned)l[3] << 16);
                    *(uint2*)&outL[go] = sl2;
                }
                if (RELUC) {
                    f4 vr;
#pragma unroll
                    for (int r = 0; r < 4; ++r) vr[r] = fmaxf(v[r], 0.f);
                    ushort_t hr[4];
#pragma unroll
                    for (int r = 0; r < 4; ++r) hr[r] = f2bf(vr[r]);
                    uint2 s2; s2.x = (unsigned)hr[0] | ((unsigned)hr[1] << 16);
                    s2.y = (unsigned)hr[2] | ((unsigned)hr[3] << 16);
                    *(uint2*)&outHr[go] = s2;
                    if (SPLIT) {
                        ushort_t lr[4];
#pragma unroll
                        for (int r = 0; r < 4; ++r) lr[r] = f2bf(vr[r] - bf2f(hr[r]));
                        uint2 s3; s3.x = (unsigned)lr[0] | ((unsigned)lr[1] << 16);
                        s3.y = (unsigned)lr[2] | ((unsigned)lr[3] << 16);
                        *(uint2*)&outLr[go] = s3;
                    }
                }
            } else {
#pragma unroll
                for (int r = 0; r < 4; ++r) {
                    int o = oc + r;
                    if (o < Cout)
                        outF[(((size_t)b * Cout + o) * Ho + oh) * Wo + ow] = v[r] + (bias ? bias[o] : 0.f);
                }
            }
        }
    }
}

// ---------------- ec1: fp32 NCHW x -> relu'd split bf16 NHWC (Cin=3) --------
__global__ __launch_bounds__(256) void ec1_k(
    const float* __restrict__ x, const float* __restrict__ wt,
    const float* __restrict__ bias, ushort_t* __restrict__ outH, ushort_t* __restrict__ outL)
{
    const int tid = threadIdx.x;
    const int p = blockIdx.x * 256 + tid;
    const int b = blockIdx.z;
    const int oc0 = blockIdx.y * 16;
    const int oh = p >> 7, ow = p & 127;

    float acc[16];
#pragma unroll
    for (int o = 0; o < 16; ++o) acc[o] = bias[oc0 + o];

    const int ih0 = oh * 2 - 1, iw0 = ow * 2 - 1;
    for (int ci = 0; ci < 3; ++ci) {
        float iv[9];
#pragma unroll
        for (int kh = 0; kh < 3; ++kh)
#pragma unroll
            for (int kw = 0; kw < 3; ++kw) {
                int ih = ih0 + kh, iw = iw0 + kw;
                bool ok = ((unsigned)ih < 256u) && ((unsigned)iw < 256u);
                iv[kh * 3 + kw] = ok ? x[(((size_t)(b * 3) + ci) * 256 + ih) * 256 + iw] : 0.f;
            }
#pragma unroll
        for (int o = 0; o < 16; ++o) {
            const float* wp = wt + ((size_t)(oc0 + o) * 3 + ci) * 9;
#pragma unroll
            for (int k = 0; k < 9; ++k) acc[o] = fmaf(iv[k], wp[k], acc[o]);
        }
    }

    size_t go = (((size_t)(b * 128) + oh) * 128 + ow) * 64 + oc0;
    unsigned uh[8], ul[8];
#pragma unroll
    for (int e = 0; e < 8; ++e) {
        float v0 = fmaxf(acc[2 * e], 0.f), v1 = fmaxf(acc[2 * e + 1], 0.f);
        ushort_t h0 = f2bf(v0), h1 = f2bf(v1);
        ushort_t g0 = f2bf(v0 - bf2f(h0)), g1 = f2bf(v1 - bf2f(h1));
        uh[e] = (unsigned)h0 | ((unsigned)h1 << 16);
        ul[e] = (unsigned)g0 | ((unsigned)g1 << 16);
    }
    uint4 s0 = {uh[0], uh[1], uh[2], uh[3]}, s1 = {uh[4], uh[5], uh[6], uh[7]};
    uint4 t0 = {ul[0], ul[1], ul[2], ul[3]}, t1 = {ul[4], ul[5], ul[6], ul[7]};
    *(uint4*)&outH[go] = s0; *(uint4*)&outH[go + 8] = s1;
    *(uint4*)&outL[go] = t0; *(uint4*)&outL[go + 8] = t1;
}

// ---------------- codebook squared norms ------------------------------------
__global__ void cnorm_k(const float* __restrict__ cb, float* __restrict__ cnorm)
{
    int k = blockIdx.x * 64 + threadIdx.x;
    float s = 0.f;
#pragma unroll
    for (int d = 0; d < 64; ++d) { float c = cb[(size_t)k * 64 + d]; s = fmaf(c, c, s); }
    cnorm[k] = s;
}

// ---------------- VQ: LDS codebook + LDS histogram (validated verbatim) -----
__global__ __launch_bounds__(256) void vq6_k(
    const ushort_t* __restrict__ zh, const ushort_t* __restrict__ zl,
    const ushort_t* __restrict__ cbh, const ushort_t* __restrict__ cbl,
    const float* __restrict__ cbf, const float* __restrict__ cn,
    ushort_t* __restrict__ qb, float* __restrict__ lsum, unsigned* __restrict__ hist)
{
    __shared__ __align__(16) ushort_t sCh[128 * 72];
    __shared__ __align__(16) ushort_t sCl[128 * 72];
    __shared__ float sE[4];
    __shared__ unsigned lh[512];

    const int tid = threadIdx.x, lane = tid & 63, wv = tid >> 6;
    const int colg = lane & 15, kh = lane >> 4;
    const int mypx = blockIdx.x * 64 + wv * 16 + colg;

    for (int i = tid; i < 512; i += 256) lh[i] = 0;

    const ushort_t* zp = zh + (size_t)mypx * 64;
    const ushort_t* zq = zl + (size_t)mypx * 64;
    bf8 bh[2], bl[2];
    bh[0] = ld8(zp + kh * 8); bh[1] = ld8(zp + kh * 8 + 32);
    bl[0] = ld8(zq + kh * 8); bl[1] = ld8(zq + kh * 8 + 32);

    float best = INFINITY; int bi = 0;

    for (int ch = 0; ch < 4; ++ch) {
        __syncthreads();
        {
            const uint4* srcH = (const uint4*)(cbh + (size_t)ch * 128 * 64);
            const uint4* srcL = (const uint4*)(cbl + (size_t)ch * 128 * 64);
            for (int u = tid; u < 1024; u += 256) {
                int code = u >> 3, sub = u & 7;
                *(uint4*)&sCh[code * 72 + sub * 8] = srcH[u];
                *(uint4*)&sCl[code * 72 + sub * 8] = srcL[u];
            }
        }
        __syncthreads();
#pragma unroll
        for (int t = 0; t < 8; ++t) {
            f4 a = (f4)(0.0f);
            const int row = (t * 16 + colg) * 72 + kh * 8;
#pragma unroll
            for (int kk = 0; kk < 2; ++kk) {
                bf8 chh = ld8(&sCh[row + kk * 32]);
                bf8 cll = ld8(&sCl[row + kk * 32]);
                a = __builtin_amdgcn_mfma_f32_16x16x32_bf16(chh, bh[kk], a, 0, 0, 0);
                a = __builtin_amdgcn_mfma_f32_16x16x32_bf16(chh, bl[kk], a, 0, 0, 0);
                a = __builtin_amdgcn_mfma_f32_16x16x32_bf16(cll, bh[kk], a, 0, 0, 0);
            }
            f4 cv = *(const f4*)(cn + ch * 128 + t * 16 + kh * 4);
#pragma unroll
            for (int r = 0; r < 4; ++r) {
                float d = cv[r] - 2.f * a[r];
                int j = ch * 128 + t * 16 + kh * 4 + r;
                if (d < best) { best = d; bi = j; }
            }
        }
    }

#pragma unroll
    for (int m = 16; m <= 32; m <<= 1) {
        float ob = __shfl_xor(best, m);
        int   oi = __shfl_xor(bi, m);
        if (ob < best || (ob == best && oi < bi)) { best = ob; bi = oi; }
    }

    float err = 0.f;
    {
        const float* cf = cbf + (size_t)bi * 64 + kh * 16;
        const ushort_t* zp2 = zp + kh * 16;
        const ushort_t* zq2 = zq + kh * 16;
        ushort_t qo[16];
#pragma unroll
        for (int e = 0; e < 16; ++e) {
            float c = cf[e];
            float z = bf2f(zp2[e]) + bf2f(zq2[e]);
            float dd = c - z;
            err = fmaf(dd, dd, err);
            qo[e] = f2bf(c);
        }
        uint4 s0, s1v;
        s0.x = (unsigned)qo[0] | ((unsigned)qo[1] << 16);
        s0.y = (unsigned)qo[2] | ((unsigned)qo[3] << 16);
        s0.z = (unsigned)qo[4] | ((unsigned)qo[5] << 16);
        s0.w = (unsigned)qo[6] | ((unsigned)qo[7] << 16);
        s1v.x = (unsigned)qo[8] | ((unsigned)qo[9] << 16);
        s1v.y = (unsigned)qo[10] | ((unsigned)qo[11] << 16);
        s1v.z = (unsigned)qo[12] | ((unsigned)qo[13] << 16);
        s1v.w = (unsigned)qo[14] | ((unsigned)qo[15] << 16);
        *(uint4*)&qb[(size_t)mypx * 64 + kh * 16] = s0;
        *(uint4*)&qb[(size_t)mypx * 64 + kh * 16 + 8] = s1v;
    }

    err += __shfl_xor(err, 16); err += __shfl_xor(err, 32);
    err += __shfl_xor(err, 1);  err += __shfl_xor(err, 2);
    err += __shfl_xor(err, 4);  err += __shfl_xor(err, 8);
    if (lane == 0) sE[wv] = err;
    if (kh == 0) atomicAdd(&lh[bi], 1u);
    __syncthreads();
    if (tid == 0) atomicAdd(lsum, (sE[0] + sE[1]) + (sE[2] + sE[3]));
    for (int i = tid; i < 512; i += 256) {
        unsigned c = lh[i];
        if (c) atomicAdd(&hist[i], c);
    }
}

// ---------------- finalize loss + perplexity --------------------------------
__global__ void fin_k(const unsigned* __restrict__ hist,
                      const float* __restrict__ loss_sum,
                      float* __restrict__ out, int out_size)
{
    __shared__ float red[512];
    int t = threadIdx.x;
    float pk = (float)hist[t] * (1.f / 32768.f);
    red[t] = pk * logf(pk + 1e-10f);
    __syncthreads();
    for (int s = 256; s; s >>= 1) {
        if (t < s) red[t] += red[t + s];
        __syncthreads();
    }
    if (t == 0) {
        out[0] = 1.25f * loss_sum[0] * (1.f / (32768.f * 64.f));
        out[out_size - 1] = expf(-red[0]);
    }
}

// ---------------------------------------------------------------------------
extern "C" void kernel_launch(void* const* d_in, const int* in_sizes, int n_in,
                              void* d_out, int out_size, void* d_ws, size_t ws_size,
                              hipStream_t stream)
{
    const float* x      = (const float*)d_in[0];
    const float* ec1_w  = (const float*)d_in[1];
    const float* ec1_b  = (const float*)d_in[2];
    const float* ec2_w  = (const float*)d_in[3];
    const float* ec2_b  = (const float*)d_in[4];
    const float* ec3_w  = (const float*)d_in[5];
    const float* ec3_b  = (const float*)d_in[6];
    const float* ec4_w  = (const float*)d_in[7];
    const float* ec4_b  = (const float*)d_in[8];
    const float* er0a_w = (const float*)d_in[9];
    const float* er0b_w = (const float*)d_in[10];
    const float* er1a_w = (const float*)d_in[11];
    const float* er1b_w = (const float*)d_in[12];
    const float* pvq_w  = (const float*)d_in[13];
    const float* pvq_b  = (const float*)d_in[14];
    const float* cbk    = (const float*)d_in[15];
    const float* dc1_w  = (const float*)d_in[16];
    const float* dc1_b  = (const float*)d_in[17];
    const float* dr0a_w = (const float*)d_in[18];
    const float* dr0b_w = (const float*)d_in[19];
    const float* dr1a_w = (const float*)d_in[20];
    const float* dr1b_w = (const float*)d_in[21];
    const float* dt1_w  = (const float*)d_in[22];
    const float* dt1_b  = (const float*)d_in[23];
    const float* dt2_w  = (const float*)d_in[24];
    const float* dt2_b  = (const float*)d_in[25];
    const float* dt3_w  = (const float*)d_in[26];
    const float* dt3_b  = (const float*)d_in[27];

    float* out = (float*)d_out;
    ushort_t* P = (ushort_t*)d_ws;

    // ---- activation arena (ushort element offsets) ----
    ushort_t* a1h  = P;               // 33,554,432 (ec1 out, relu'd)
    ushort_t* a1l  = P + 33554432;
    ushort_t* a2h  = P + 67108864;    // 16,777,216 (ec2 out, relu'd)
    ushort_t* a2l  = P + 83886080;    // ends 100,663,296
    ushort_t* a3h  = P;               //  4,194,304 (ec3 out, relu'd)
    ushort_t* a3l  = P + 4194304;
    ushort_t* a4h  = P + 8388608;     //  raw
    ushort_t* a4l  = P + 12582912;
    ushort_t* a4rh = P + 16777216;    //  relu copy
    ushort_t* a4rl = P + 20971520;
    ushort_t* th   = P + 25165824;    //  1,048,576 (res hidden)
    ushort_t* tl   = P + 26214400;
    ushort_t* zh   = P + 27262976;    //  2,097,152
    ushort_t* zl   = P + 29360128;
    ushort_t* qb   = P + 31457280;    //  2,097,152
    ushort_t* d1h  = P + 33554432;    //  4,194,304 (decoder raw)
    ushort_t* d1r  = P + 37748736;    //  relu copy
    ushort_t* t2   = P + 41943040;    //  1,048,576
    ushort_t* u1   = P + 42991616;    //  8,388,608
    ushort_t* u2   = P + 51380224;    // 33,554,432 ends 84,934,656

    // ---- weight arena (fragment-major) ----
    size_t wc = 100663296;
    auto walloc = [&](size_t n) { ushort_t* p = P + wc; wc += n; return p; };
    ushort_t* W_ec2h = walloc(73728);  ushort_t* W_ec2l = walloc(73728);
    ushort_t* W_ec3h = walloc(147456); ushort_t* W_ec3l = walloc(147456);
    ushort_t* W_ec4h = walloc(147456); ushort_t* W_ec4l = walloc(147456);
    ushort_t* W_r0ah = walloc(36864);  ushort_t* W_r0al = walloc(36864);
    ushort_t* W_r0bh = walloc(4096);   ushort_t* W_r0bl = walloc(4096);
    ushort_t* W_r1ah = walloc(36864);  ushort_t* W_r1al = walloc(36864);
    ushort_t* W_r1bh = walloc(4096);   ushort_t* W_r1bl = walloc(4096);
    ushort_t* W_pvqh = walloc(8192);   ushort_t* W_pvql = walloc(8192);
    ushort_t* W_cbh  = walloc(32768);  ushort_t* W_cbl  = walloc(32768);
    ushort_t* W_dc1  = walloc(73728);
    ushort_t* W_d0a  = walloc(36864);
    ushort_t* W_d0b  = walloc(4096);
    ushort_t* W_d1a  = walloc(36864);
    ushort_t* W_d1b  = walloc(4096);
    ushort_t* W_dt1  = walloc(73728);
    ushort_t* W_dt2  = walloc(36864);
    ushort_t* W_dt3  = walloc(9216);

    wc = (wc + 7) & ~(size_t)7;
    float* cn = (float*)(P + wc);               // 512
    float* ls = cn + 512;                       // 1
    unsigned* hist = (unsigned*)(ls + 1);       // 512

    // ---- fused weight prep ----
    PrepTab tab = {}; tab.ne = 17;
    int cum = 0, ei = 0;
    auto addp = [&](const float* src, ushort_t* dh, ushort_t* dl, int O, int I, int T, int mode, int frag) {
        PrepEnt& e = tab.e[ei++];
        e.src = src; e.dh = (long)(dh - P); e.dl = dl ? (long)(dl - P) : -1;
        e.O = O; e.I = I; e.T = T; e.mode = mode; e.frag = frag;
        e.n = frag ? ((O + 15) / 16) * T * (I / 32) * 512 : O * I * T;
        e.blk0 = cum; cum += (e.n + 255) / 256;
    };
    addp(ec2_w, W_ec2h, W_ec2l, 128, 64, 9, 0, 1);
    addp(ec3_w, W_ec3h, W_ec3l, 128, 128, 9, 0, 1);
    addp(ec4_w, W_ec4h, W_ec4l, 128, 128, 9, 0, 1);
    addp(er0a_w, W_r0ah, W_r0al, 32, 128, 9, 0, 1);
    addp(er0b_w, W_r0bh, W_r0bl, 128, 32, 1, 0, 1);
    addp(er1a_w, W_r1ah, W_r1al, 32, 128, 9, 0, 1);
    addp(er1b_w, W_r1bh, W_r1bl, 128, 32, 1, 0, 1);
    addp(pvq_w, W_pvqh, W_pvql, 64, 128, 1, 0, 1);
    addp(cbk, W_cbh, W_cbl, 512, 64, 1, 0, 0);
    addp(dc1_w, W_dc1, nullptr, 128, 64, 9, 0, 1);
    addp(dr0a_w, W_d0a, nullptr, 32, 128, 9, 0, 1);
    addp(dr0b_w, W_d0b, nullptr, 128, 32, 1, 0, 1);
    addp(dr1a_w, W_d1a, nullptr, 32, 128, 9, 0, 1);
    addp(dr1b_w, W_d1b, nullptr, 128, 32, 1, 0, 1);
    addp(dt1_w, W_dt1, nullptr, 64, 128, 9, 1, 1);
    addp(dt2_w, W_dt2, nullptr, 64, 64, 9, 1, 1);
    addp(dt3_w, W_dt3, nullptr, 3, 64, 9, 1, 1);

    hipMemsetAsync(ls, 0, 4 * 513, stream);
    prep_all_k<<<cum, 256, 0, stream>>>(P, tab);
    cnorm_k<<<8, 64, 0, stream>>>(cbk, cn);

    // ---- encoder (DBUF=0 everywhere: z bit-path identical to validated) ----
    ec1_k<<<dim3(64, 4, 32), 256, 0, stream>>>(x, ec1_w, ec1_b, a1h, a1l);
    // template: <MT,MW,NW,S,TT,SPLIT,ADD_RES,RELU_OUT,RELUC,OUT_MODE,MGUARD,DBUF>
    hconv2<4,2,2, 2,0, 1,0,1,0, 0,0, 0><<<dim3(64, 1, 32), 256, 0, stream>>>(   // ec2
        a1h, a1l, W_ec2h, W_ec2l, ec2_b, nullptr, nullptr,
        a2h, a2l, nullptr, nullptr, nullptr, 64, 128, 128, 128, 64, 64);
    hconv2<4,2,2, 2,0, 1,0,1,0, 0,0, 0><<<dim3(16, 1, 32), 256, 0, stream>>>(   // ec3
        a2h, a2l, W_ec3h, W_ec3l, ec3_b, nullptr, nullptr,
        a3h, a3l, nullptr, nullptr, nullptr, 128, 64, 64, 128, 32, 32);
    hconv2<2,2,2, 1,0, 1,0,0,1, 0,0, 0><<<dim3(16, 2, 32), 256, 0, stream>>>(   // ec4: raw + relu copy
        a3h, a3l, W_ec4h, W_ec4l, ec4_b, nullptr, nullptr,
        a4h, a4l, a4rh, a4rl, nullptr, 128, 32, 32, 128, 32, 32);
    hconv2<1,2,2, 1,0, 1,0,1,0, 0,0, 0><<<dim3(16, 1, 32), 256, 0, stream>>>(   // er0a
        a4rh, a4rl, W_r0ah, W_r0al, nullptr, nullptr, nullptr,
        th, tl, nullptr, nullptr, nullptr, 128, 32, 32, 32, 32, 32);
    hconv2<2,2,2, 1,1, 1,1,0,1, 0,0, 0><<<dim3(16, 2, 32), 256, 0, stream>>>(   // er0b: +res, raw+relu
        th, tl, W_r0bh, W_r0bl, nullptr, a4h, a4l,
        a4h, a4l, a4rh, a4rl, nullptr, 32, 32, 32, 128, 32, 32);
    hconv2<1,2,2, 1,0, 1,0,1,0, 0,0, 0><<<dim3(16, 1, 32), 256, 0, stream>>>(   // er1a
        a4rh, a4rl, W_r1ah, W_r1al, nullptr, nullptr, nullptr,
        th, tl, nullptr, nullptr, nullptr, 128, 32, 32, 32, 32, 32);
    hconv2<2,2,2, 1,1, 1,1,1,0, 0,0, 0><<<dim3(16, 2, 32), 256, 0, stream>>>(   // er1b: +res, relu'd
        th, tl, W_r1bh, W_r1bl, nullptr, a4h, a4l,
        a4rh, a4rl, nullptr, nullptr, nullptr, 32, 32, 32, 128, 32, 32);
    hconv2<1,2,2, 1,1, 1,0,0,0, 0,0, 0><<<dim3(16, 2, 32), 256, 0, stream>>>(   // pvq 1x1
        a4rh, a4rl, W_pvqh, W_pvql, pvq_b, nullptr, nullptr,
        zh, zl, nullptr, nullptr, nullptr, 128, 32, 32, 64, 32, 32);

    // ---- VQ (writes hist/lsum: outputs 0,2 finalized before decoder) ----
    vq6_k<<<512, 256, 0, stream>>>(zh, zl, W_cbh, W_cbl, cbk, cn, qb, ls, hist);

    // ---- decoder (DBUF=1 on multi-chunk layers; cannot affect outputs 0/2) --
    hconv2<2,2,2, 1,0, 0,0,0,1, 0,0, 1><<<dim3(16, 2, 32), 256, 0, stream>>>(   // dc1 (DBUF)
        qb, nullptr, W_dc1, nullptr, dc1_b, nullptr, nullptr,
        d1h, nullptr, d1r, nullptr, nullptr, 64, 32, 32, 128, 32, 32);
    hconv2<1,2,2, 1,0, 0,0,1,0, 0,0, 1><<<dim3(16, 1, 32), 256, 0, stream>>>(   // dr0a (DBUF)
        d1r, nullptr, W_d0a, nullptr, nullptr, nullptr, nullptr,
        t2, nullptr, nullptr, nullptr, nullptr, 128, 32, 32, 32, 32, 32);
    hconv2<2,2,2, 1,1, 0,1,0,1, 0,0, 0><<<dim3(16, 2, 32), 256, 0, stream>>>(   // dr0b (nch=1)
        t2, nullptr, W_d0b, nullptr, nullptr, d1h, nullptr,
        d1h, nullptr, d1r, nullptr, nullptr, 32, 32, 32, 128, 32, 32);
    hconv2<1,2,2, 1,0, 0,0,1,0, 0,0, 1><<<dim3(16, 1, 32), 256, 0, stream>>>(   // dr1a (DBUF)
        d1r, nullptr, W_d1a, nullptr, nullptr, nullptr, nullptr,
        t2, nullptr, nullptr, nullptr, nullptr, 128, 32, 32, 32, 32, 32);
    hconv2<2,2,2, 1,1, 0,1,1,0, 0,0, 0><<<dim3(16, 2, 32), 256, 0, stream>>>(   // dr1b (nch=1)
        t2, nullptr, W_d1b, nullptr, nullptr, d1h, nullptr,
        d1r, nullptr, nullptr, nullptr, nullptr, 32, 32, 32, 128, 32, 32);
    hconv2<2,2,2, 1,2, 0,0,1,0, 0,0, 1><<<dim3(16, 1, 32), 256, 0, stream>>>(   // dt1 (convT, DBUF)
        d1r, nullptr, W_dt1, nullptr, dt1_b, nullptr, nullptr,
        u1, nullptr, nullptr, nullptr, nullptr, 128, 32, 32, 64, 32, 32);
    hconv2<2,2,2, 1,2, 0,0,1,0, 0,0, 1><<<dim3(64, 1, 32), 256, 0, stream>>>(   // dt2 (convT, DBUF)
        u1, nullptr, W_dt2, nullptr, dt2_b, nullptr, nullptr,
        u2, nullptr, nullptr, nullptr, nullptr, 64, 64, 64, 64, 64, 64);
    hconv2<1,1,4, 1,2, 0,0,0,0, 1,1, 1><<<dim3(128, 1, 32), 256, 0, stream>>>(  // dt3 -> fp32 NCHW (DBUF)
        u2, nullptr, W_dt3, nullptr, dt3_b, nullptr, nullptr,
        nullptr, nullptr, nullptr, nullptr, out + 1, 64, 128, 128, 3, 128, 128);

    // ---- scalars ----
    fin_k<<<1, 512, 0, stream>>>(hist, ls, out, out_size);
}

// Round 17
// 577.854 us; speedup vs baseline: 1.0863x; 1.0863x over previous
//
#include <hip/hip_runtime.h>
#include <math.h>

// ---------------------------------------------------------------------------
// VQ-VAE forward, round 17: round-12 structure with FULL 4-term split-bf16
// dot products in the encoder convs AND vq (adds the al*bl term).
// Rationale: the byte-identical round-12 binary fails stochastically
// (absmax draws 0.111/0.156 across runs of identical code) -> bit-freezing
// is worthless; the only defense is margin. Round-5 showed exact re-rank
// doesn't help => the ~3 baseline argmin flips come from z error (dropped
// al*bl term, ~2^-16/layer). 4-term -> ~2^-18/layer -> ~4x fewer flips ->
// expected absmax ~0.02-0.06 with 2-4 flips of threshold headroom.
// ---------------------------------------------------------------------------

typedef unsigned short ushort_t;
typedef __bf16 bf8 __attribute__((ext_vector_type(8)));
typedef float f4 __attribute__((ext_vector_type(4)));

__device__ __forceinline__ float bf2f(ushort_t u) {
    union { unsigned u; float f; } c; c.u = ((unsigned)u) << 16; return c.f;
}
__device__ __forceinline__ ushort_t f2bf(float f) {
    union { float f; unsigned u; } c; c.f = f; unsigned x = c.u;
    return (ushort_t)((x + 0x7fffu + ((x >> 16) & 1u)) >> 16);
}
__device__ __forceinline__ bf8 ld8(const ushort_t* p) { return *(const bf8*)p; }

// ---------------- fused weight prep ----------------------------------------
struct PrepEnt { const float* src; long dh, dl; int O, I, T, mode, frag, blk0, n; };
struct PrepTab { PrepEnt e[17]; int ne; };

__global__ __launch_bounds__(256) void prep_all_k(ushort_t* __restrict__ P, PrepTab tab)
{
    int bid = blockIdx.x, ei = 0;
    for (int i = 1; i < tab.ne; ++i) if (bid >= tab.e[i].blk0) ei = i;
    PrepEnt e = tab.e[ei];
    int id = (bid - e.blk0) * 256 + threadIdx.x;
    if (id >= e.n) return;
    float v = 0.f;
    if (e.frag) {
        int pos = id & 511, tile = id >> 9;
        int nch = e.I >> 5;
        int ch = tile % nch, rest = tile / nch;
        int t = rest % e.T, ob = rest / e.T;
        int ln = pos >> 3, el = pos & 7;
        int o = ob * 16 + (ln & 15);
        int i2 = ch * 32 + (ln >> 4) * 8 + el;
        if (o < e.O)
            v = e.mode ? e.src[((size_t)i2 * e.O + o) * e.T + t]
                       : e.src[((size_t)o * e.I + i2) * e.T + t];
    } else {
        int i2 = id % e.I; int rest = id / e.I; int t = rest % e.T; int o = rest / e.T;
        v = e.mode ? e.src[((size_t)i2 * e.O + o) * e.T + t]
                   : e.src[((size_t)o * e.I + i2) * e.T + t];
    }
    ushort_t h = f2bf(v);
    P[e.dh + id] = h;
    if (e.dl >= 0) P[e.dl + id] = f2bf(v - bf2f(h));
}

// ---------------- halo-staged MFMA conv -------------------------------------
// TT: 0 = 3x3 (stride S, pad 1), 1 = 1x1, 2 = convT k3 s2 p1 op1 (parity-fused)
template<int MT,int MW,int NW,int S,int TT,int SPLIT,int ADD_RES,int RELU_OUT,int RELUC,int OUT_MODE,int MGUARD>
__global__ __launch_bounds__(MW*NW*64) void hconv(
    const ushort_t* __restrict__ inH, const ushort_t* __restrict__ inL,
    const ushort_t* __restrict__ wH,  const ushort_t* __restrict__ wL,
    const float* __restrict__ bias,
    const ushort_t* __restrict__ resH, const ushort_t* __restrict__ resL,
    ushort_t* __restrict__ outH, ushort_t* __restrict__ outL,
    ushort_t* __restrict__ outHr, ushort_t* __restrict__ outLr,
    float* __restrict__ outF,
    int Cin, int Hin, int Win, int Cout, int Hg, int Wg)
{
    constexpr int NT  = (TT == 1) ? 1 : 9;
    constexpr int RH  = (TT == 1) ? NW : (TT == 2 ? NW + 1 : (S == 2 ? 2 * NW + 1 : NW + 2));
    constexpr int RWn = (TT == 1) ? 32 : (TT == 2 ? 33 : (S == 2 ? 65 : 34));
    constexpr int CIP = 40;
    constexpr int TH  = MW * NW * 64;
    constexpr int NJ  = (TT == 2) ? 8 : 2;
    constexpr int DMN = (TT == 0) ? -1 : 0;

    __shared__ __align__(16) ushort_t sH[RH * RWn * CIP];
    __shared__ __align__(16) ushort_t sL[SPLIT ? RH * RWn * CIP : 8];

    const int tid = threadIdx.x, b = blockIdx.z;
    const int oc0 = blockIdx.y * (MW * MT * 16);
    const int ncx = Wg >> 5;
    const int ow0 = ((int)blockIdx.x % ncx) * 32;
    const int sh0 = ((int)blockIdx.x / ncx) * NW;
    const int wv = tid >> 6, lane = tid & 63;
    const int wm = wv % MW, wn = wv / MW;
    const int colg = lane & 15, kh = lane >> 4;
    const int sh = sh0 + wn;

    // zero-init LDS: any staging gap reads deterministic 0 (pad convention)
    {
        uint4 zz = {0, 0, 0, 0};
        for (int u = tid; u < RH * RWn * CIP / 8; u += TH) {
            *(uint4*)&sH[u * 8] = zz;
            if (SPLIT) *(uint4*)&sL[u * 8] = zz;
        }
    }

    f4 acc[MT][NJ];
#pragma unroll
    for (int i = 0; i < MT; ++i)
#pragma unroll
        for (int g = 0; g < NJ; ++g) acc[i][g] = (f4)(0.0f);

    const ushort_t* inB  = inH + (size_t)b * Hin * Win * Cin;
    const ushort_t* inBL = SPLIT ? inL + (size_t)b * Hin * Win * Cin : nullptr;
    const int nch = Cin >> 5;
    const int ihb = sh0 * S + DMN, iwb = ow0 * S + DMN;
    const int ocb16base = (oc0 >> 4) + wm * MT;

    for (int c = 0; c < nch; ++c) {
        __syncthreads();
        for (int u = tid; u < RH * RWn * 4; u += TH) {
            int pix = u >> 2, sub = u & 3;
            int rl = pix / RWn, cl = pix % RWn;
            int ih = ihb + rl, iw = iwb + cl;
            bool ok = ((unsigned)ih < (unsigned)Hin) && ((unsigned)iw < (unsigned)Win);
            uint4 z = {0, 0, 0, 0};
            uint4 vh = ok ? *(const uint4*)(inB + ((size_t)ih * Win + iw) * Cin + c * 32 + sub * 8) : z;
            *(uint4*)&sH[(rl * RWn + cl) * CIP + sub * 8] = vh;
            if (SPLIT) {
                uint4 vl = ok ? *(const uint4*)(inBL + ((size_t)ih * Win + iw) * Cin + c * 32 + sub * 8) : z;
                *(uint4*)&sL[(rl * RWn + cl) * CIP + sub * 8] = vl;
            }
        }
        __syncthreads();
#pragma unroll
        for (int t = 0; t < NT; ++t) {
            int tdy, tdx, jb;
            if (TT == 0)      { tdy = t / 3 - 1; tdx = t % 3 - 1; jb = 0; }
            else if (TT == 1) { tdy = 0; tdx = 0; jb = 0; }
            else {
                int khw = t / 3, kww = t % 3;
                tdy = (khw == 0) ? 1 : 0; tdx = (kww == 0) ? 1 : 0;
                int po = (khw == 1) ? 0 : 1, pw = (kww == 1) ? 0 : 1;
                jb = (po * 2 + pw) * 2;
            }
            const int rl = wn * S + tdy - DMN;
            const int cbs = (TT == 0) ? (tdx + 1) : ((TT == 1) ? 0 : tdx);
            const ushort_t* bp  = &sH[rl * RWn * CIP];
            const ushort_t* bpl = SPLIT ? &sL[rl * RWn * CIP] : nullptr;
            bf8 bh[2], bl[2], ah[MT], al[MT];
#pragma unroll
            for (int jj = 0; jj < 2; ++jj) {
                bh[jj] = ld8(bp + (cbs + (jj * 16 + colg) * S) * CIP + kh * 8);
                if (SPLIT) bl[jj] = ld8(bpl + (cbs + (jj * 16 + colg) * S) * CIP + kh * 8);
            }
            const size_t aoff = (((size_t)ocb16base * NT + t) * nch + c) * 512 + lane * 8;
            const size_t astp = (size_t)NT * nch * 512;
#pragma unroll
            for (int i = 0; i < MT; ++i) {
                ah[i] = ld8(wH + aoff + i * astp);
                if (SPLIT) al[i] = ld8(wL + aoff + i * astp);
            }
#pragma unroll
            for (int i = 0; i < MT; ++i)
#pragma unroll
                for (int jj = 0; jj < 2; ++jj) {
                    acc[i][jb + jj] = __builtin_amdgcn_mfma_f32_16x16x32_bf16(ah[i], bh[jj], acc[i][jb + jj], 0, 0, 0);
                    if (SPLIT) {
                        acc[i][jb + jj] = __builtin_amdgcn_mfma_f32_16x16x32_bf16(ah[i], bl[jj], acc[i][jb + jj], 0, 0, 0);
                        acc[i][jb + jj] = __builtin_amdgcn_mfma_f32_16x16x32_bf16(al[i], bh[jj], acc[i][jb + jj], 0, 0, 0);
                        acc[i][jb + jj] = __builtin_amdgcn_mfma_f32_16x16x32_bf16(al[i], bl[jj], acc[i][jb + jj], 0, 0, 0);  // 4th term
                    }
                }
        }
    }

    const int Ho = (TT == 2) ? 2 * Hg : Hg;
    const int Wo = (TT == 2) ? 2 * Wg : Wg;
#pragma unroll
    for (int i = 0; i < MT; ++i) {
        const int ocl = wm * MT * 16 + i * 16 + kh * 4;
        const int oc  = oc0 + ocl;
        f4 bv = (f4)(0.0f);
        if (OUT_MODE == 0 && !MGUARD && bias) bv = *(const f4*)(bias + oc);
#pragma unroll
        for (int g = 0; g < NJ; ++g) {
            const int po = (TT == 2) ? (g >> 2) : 0;
            const int pw = (TT == 2) ? ((g >> 1) & 1) : 0;
            const int jj = (TT == 2) ? (g & 1) : g;
            const int sw = jj * 16 + colg;
            const int oh = (TT == 2) ? (2 * sh + po) : sh;
            const int ow = (TT == 2) ? (2 * sw + pw) : sw;
            f4 v = acc[i][g];
#pragma unroll
            for (int r = 0; r < 4; ++r) v[r] += bv[r];
            if (OUT_MODE == 0) {
                size_t go = (((size_t)b * Ho + oh) * Wo + ow) * (size_t)Cout + oc;
                if (ADD_RES) {
                    uint2 rh = *(const uint2*)&resH[go];
                    v[0] += bf2f((ushort_t)(rh.x & 0xffffu));
                    v[1] += bf2f((ushort_t)(rh.x >> 16));
                    v[2] += bf2f((ushort_t)(rh.y & 0xffffu));
                    v[3] += bf2f((ushort_t)(rh.y >> 16));
                    if (SPLIT) {
                        uint2 rlv = *(const uint2*)&resL[go];
                        v[0] += bf2f((ushort_t)(rlv.x & 0xffffu));
                        v[1] += bf2f((ushort_t)(rlv.x >> 16));
                        v[2] += bf2f((ushort_t)(rlv.y & 0xffffu));
                        v[3] += bf2f((ushort_t)(rlv.y >> 16));
                    }
                }
                if (RELU_OUT) {
#pragma unroll
                    for (int r = 0; r < 4; ++r) v[r] = fmaxf(v[r], 0.f);
                }
                ushort_t h[4];
#pragma unroll
                for (int r = 0; r < 4; ++r) h[r] = f2bf(v[r]);
                uint2 shv; shv.x = (unsigned)h[0] | ((unsigned)h[1] << 16);
                shv.y = (unsigned)h[2] | ((unsigned)h[3] << 16);
                *(uint2*)&outH[go] = shv;
                if (SPLIT) {
                    ushort_t l[4];
#pragma unroll
                    for (int r = 0; r < 4; ++r) l[r] = f2bf(v[r] - bf2f(h[r]));
                    uint2 sl2; sl2.x = (unsigned)l[0] | ((unsigned)l[1] << 16);
                    sl2.y = (unsigned)l[2] | ((unsigned)l[3] << 16);
                    *(uint2*)&outL[go] = sl2;
                }
                if (RELUC) {
                    f4 vr;
#pragma unroll
                    for (int r = 0; r < 4; ++r) vr[r] = fmaxf(v[r], 0.f);
                    ushort_t hr[4];
#pragma unroll
                    for (int r = 0; r < 4; ++r) hr[r] = f2bf(vr[r]);
                    uint2 s2; s2.x = (unsigned)hr[0] | ((unsigned)hr[1] << 16);
                    s2.y = (unsigned)hr[2] | ((unsigned)hr[3] << 16);
                    *(uint2*)&outHr[go] = s2;
                    if (SPLIT) {
                        ushort_t lr[4];
#pragma unroll
                        for (int r = 0; r < 4; ++r) lr[r] = f2bf(vr[r] - bf2f(hr[r]));
                        uint2 s3; s3.x = (unsigned)lr[0] | ((unsigned)lr[1] << 16);
                        s3.y = (unsigned)lr[2] | ((unsigned)lr[3] << 16);
                        *(uint2*)&outLr[go] = s3;
                    }
                }
            } else {
#pragma unroll
                for (int r = 0; r < 4; ++r) {
                    int o = oc + r;
                    if (o < Cout)
                        outF[(((size_t)b * Cout + o) * Ho + oh) * Wo + ow] = v[r] + (bias ? bias[o] : 0.f);
                }
            }
        }
    }
}

// ---------------- ec1: fp32 NCHW x -> relu'd split bf16 NHWC (Cin=3) --------
__global__ __launch_bounds__(256) void ec1_k(
    const float* __restrict__ x, const float* __restrict__ wt,
    const float* __restrict__ bias, ushort_t* __restrict__ outH, ushort_t* __restrict__ outL)
{
    const int tid = threadIdx.x;
    const int p = blockIdx.x * 256 + tid;
    const int b = blockIdx.z;
    const int oc0 = blockIdx.y * 16;
    const int oh = p >> 7, ow = p & 127;

    float acc[16];
#pragma unroll
    for (int o = 0; o < 16; ++o) acc[o] = bias[oc0 + o];

    const int ih0 = oh * 2 - 1, iw0 = ow * 2 - 1;
    for (int ci = 0; ci < 3; ++ci) {
        float iv[9];
#pragma unroll
        for (int kh = 0; kh < 3; ++kh)
#pragma unroll
            for (int kw = 0; kw < 3; ++kw) {
                int ih = ih0 + kh, iw = iw0 + kw;
                bool ok = ((unsigned)ih < 256u) && ((unsigned)iw < 256u);
                iv[kh * 3 + kw] = ok ? x[(((size_t)(b * 3) + ci) * 256 + ih) * 256 + iw] : 0.f;
            }
#pragma unroll
        for (int o = 0; o < 16; ++o) {
            const float* wp = wt + ((size_t)(oc0 + o) * 3 + ci) * 9;
#pragma unroll
            for (int k = 0; k < 9; ++k) acc[o] = fmaf(iv[k], wp[k], acc[o]);
        }
    }

    size_t go = (((size_t)(b * 128) + oh) * 128 + ow) * 64 + oc0;
    unsigned uh[8], ul[8];
#pragma unroll
    for (int e = 0; e < 8; ++e) {
        float v0 = fmaxf(acc[2 * e], 0.f), v1 = fmaxf(acc[2 * e + 1], 0.f);
        ushort_t h0 = f2bf(v0), h1 = f2bf(v1);
        ushort_t g0 = f2bf(v0 - bf2f(h0)), g1 = f2bf(v1 - bf2f(h1));
        uh[e] = (unsigned)h0 | ((unsigned)h1 << 16);
        ul[e] = (unsigned)g0 | ((unsigned)g1 << 16);
    }
    uint4 s0 = {uh[0], uh[1], uh[2], uh[3]}, s1 = {uh[4], uh[5], uh[6], uh[7]};
    uint4 t0 = {ul[0], ul[1], ul[2], ul[3]}, t1 = {ul[4], ul[5], ul[6], ul[7]};
    *(uint4*)&outH[go] = s0; *(uint4*)&outH[go + 8] = s1;
    *(uint4*)&outL[go] = t0; *(uint4*)&outL[go + 8] = t1;
}

// ---------------- codebook squared norms ------------------------------------
__global__ void cnorm_k(const float* __restrict__ cb, float* __restrict__ cnorm)
{
    int k = blockIdx.x * 64 + threadIdx.x;
    float s = 0.f;
#pragma unroll
    for (int d = 0; d < 64; ++d) { float c = cb[(size_t)k * 64 + d]; s = fmaf(c, c, s); }
    cnorm[k] = s;
}

// ---------------- VQ: LDS codebook + LDS histogram, 4-term exact split dot --
__global__ __launch_bounds__(256) void vq7_k(
    const ushort_t* __restrict__ zh, const ushort_t* __restrict__ zl,
    const ushort_t* __restrict__ cbh, const ushort_t* __restrict__ cbl,
    const float* __restrict__ cbf, const float* __restrict__ cn,
    ushort_t* __restrict__ qb, float* __restrict__ lsum, unsigned* __restrict__ hist)
{
    __shared__ __align__(16) ushort_t sCh[128 * 72];
    __shared__ __align__(16) ushort_t sCl[128 * 72];
    __shared__ float sE[4];
    __shared__ unsigned lh[512];

    const int tid = threadIdx.x, lane = tid & 63, wv = tid >> 6;
    const int colg = lane & 15, kh = lane >> 4;
    const int mypx = blockIdx.x * 64 + wv * 16 + colg;

    for (int i = tid; i < 512; i += 256) lh[i] = 0;

    const ushort_t* zp = zh + (size_t)mypx * 64;
    const ushort_t* zq = zl + (size_t)mypx * 64;
    bf8 bh[2], bl[2];
    bh[0] = ld8(zp + kh * 8); bh[1] = ld8(zp + kh * 8 + 32);
    bl[0] = ld8(zq + kh * 8); bl[1] = ld8(zq + kh * 8 + 32);

    float best = INFINITY; int bi = 0;

    for (int ch = 0; ch < 4; ++ch) {
        __syncthreads();
        {
            const uint4* srcH = (const uint4*)(cbh + (size_t)ch * 128 * 64);
            const uint4* srcL = (const uint4*)(cbl + (size_t)ch * 128 * 64);
            for (int u = tid; u < 1024; u += 256) {
                int code = u >> 3, sub = u & 7;
                *(uint4*)&sCh[code * 72 + sub * 8] = srcH[u];
                *(uint4*)&sCl[code * 72 + sub * 8] = srcL[u];
            }
        }
        __syncthreads();
#pragma unroll
        for (int t = 0; t < 8; ++t) {
            f4 a = (f4)(0.0f);
            const int row = (t * 16 + colg) * 72 + kh * 8;
#pragma unroll
            for (int kk = 0; kk < 2; ++kk) {
                bf8 chh = ld8(&sCh[row + kk * 32]);
                bf8 cll = ld8(&sCl[row + kk * 32]);
                a = __builtin_amdgcn_mfma_f32_16x16x32_bf16(chh, bh[kk], a, 0, 0, 0);
                a = __builtin_amdgcn_mfma_f32_16x16x32_bf16(chh, bl[kk], a, 0, 0, 0);
                a = __builtin_amdgcn_mfma_f32_16x16x32_bf16(cll, bh[kk], a, 0, 0, 0);
                a = __builtin_amdgcn_mfma_f32_16x16x32_bf16(cll, bl[kk], a, 0, 0, 0);  // 4th term
            }
            f4 cv = *(const f4*)(cn + ch * 128 + t * 16 + kh * 4);
#pragma unroll
            for (int r = 0; r < 4; ++r) {
                float d = cv[r] - 2.f * a[r];
                int j = ch * 128 + t * 16 + kh * 4 + r;
                if (d < best) { best = d; bi = j; }
            }
        }
    }

    // merge across the 4 kh-groups (same pixel, disjoint code subsets)
#pragma unroll
    for (int m = 16; m <= 32; m <<= 1) {
        float ob = __shfl_xor(best, m);
        int   oi = __shfl_xor(bi, m);
        if (ob < best || (ob == best && oi < bi)) { best = ob; bi = oi; }
    }

    // epilogue: 4 lanes per pixel; lane handles dims [kh*16, kh*16+16)
    float err = 0.f;
    {
        const float* cf = cbf + (size_t)bi * 64 + kh * 16;
        const ushort_t* zp2 = zp + kh * 16;
        const ushort_t* zq2 = zq + kh * 16;
        ushort_t qo[16];
#pragma unroll
        for (int e = 0; e < 16; ++e) {
            float c = cf[e];
            float z = bf2f(zp2[e]) + bf2f(zq2[e]);
            float dd = c - z;
            err = fmaf(dd, dd, err);
            qo[e] = f2bf(c);
        }
        uint4 s0, s1v;
        s0.x = (unsigned)qo[0] | ((unsigned)qo[1] << 16);
        s0.y = (unsigned)qo[2] | ((unsigned)qo[3] << 16);
        s0.z = (unsigned)qo[4] | ((unsigned)qo[5] << 16);
        s0.w = (unsigned)qo[6] | ((unsigned)qo[7] << 16);
        s1v.x = (unsigned)qo[8] | ((unsigned)qo[9] << 16);
        s1v.y = (unsigned)qo[10] | ((unsigned)qo[11] << 16);
        s1v.z = (unsigned)qo[12] | ((unsigned)qo[13] << 16);
        s1v.w = (unsigned)qo[14] | ((unsigned)qo[15] << 16);
        *(uint4*)&qb[(size_t)mypx * 64 + kh * 16] = s0;
        *(uint4*)&qb[(size_t)mypx * 64 + kh * 16 + 8] = s1v;
    }

    err += __shfl_xor(err, 16); err += __shfl_xor(err, 32);
    err += __shfl_xor(err, 1);  err += __shfl_xor(err, 2);
    err += __shfl_xor(err, 4);  err += __shfl_xor(err, 8);
    if (lane == 0) sE[wv] = err;
    if (kh == 0) atomicAdd(&lh[bi], 1u);     // LDS atomic: block-local
    __syncthreads();
    if (tid == 0) atomicAdd(lsum, (sE[0] + sE[1]) + (sE[2] + sE[3]));
    for (int i = tid; i < 512; i += 256) {
        unsigned c = lh[i];
        if (c) atomicAdd(&hist[i], c);       // <=512 adds per bin total
    }
}

// ---------------- finalize loss + perplexity --------------------------------
__global__ void fin_k(const unsigned* __restrict__ hist,
                      const float* __restrict__ loss_sum,
                      float* __restrict__ out, int out_size)
{
    __shared__ float red[512];
    int t = threadIdx.x;
    float pk = (float)hist[t] * (1.f / 32768.f);
    red[t] = pk * logf(pk + 1e-10f);
    __syncthreads();
    for (int s = 256; s; s >>= 1) {
        if (t < s) red[t] += red[t + s];
        __syncthreads();
    }
    if (t == 0) {
        out[0] = 1.25f * loss_sum[0] * (1.f / (32768.f * 64.f));
        out[out_size - 1] = expf(-red[0]);
    }
}

// ---------------------------------------------------------------------------
extern "C" void kernel_launch(void* const* d_in, const int* in_sizes, int n_in,
                              void* d_out, int out_size, void* d_ws, size_t ws_size,
                              hipStream_t stream)
{
    const float* x      = (const float*)d_in[0];
    const float* ec1_w  = (const float*)d_in[1];
    const float* ec1_b  = (const float*)d_in[2];
    const float* ec2_w  = (const float*)d_in[3];
    const float* ec2_b  = (const float*)d_in[4];
    const float* ec3_w  = (const float*)d_in[5];
    const float* ec3_b  = (const float*)d_in[6];
    const float* ec4_w  = (const float*)d_in[7];
    const float* ec4_b  = (const float*)d_in[8];
    const float* er0a_w = (const float*)d_in[9];
    const float* er0b_w = (const float*)d_in[10];
    const float* er1a_w = (const float*)d_in[11];
    const float* er1b_w = (const float*)d_in[12];
    const float* pvq_w  = (const float*)d_in[13];
    const float* pvq_b  = (const float*)d_in[14];
    const float* cbk    = (const float*)d_in[15];
    const float* dc1_w  = (const float*)d_in[16];
    const float* dc1_b  = (const float*)d_in[17];
    const float* dr0a_w = (const float*)d_in[18];
    const float* dr0b_w = (const float*)d_in[19];
    const float* dr1a_w = (const float*)d_in[20];
    const float* dr1b_w = (const float*)d_in[21];
    const float* dt1_w  = (const float*)d_in[22];
    const float* dt1_b  = (const float*)d_in[23];
    const float* dt2_w  = (const float*)d_in[24];
    const float* dt2_b  = (const float*)d_in[25];
    const float* dt3_w  = (const float*)d_in[26];
    const float* dt3_b  = (const float*)d_in[27];

    float* out = (float*)d_out;
    ushort_t* P = (ushort_t*)d_ws;

    // ---- activation arena (ushort element offsets) ----
    ushort_t* a1h  = P;               // 33,554,432 (ec1 out, relu'd)
    ushort_t* a1l  = P + 33554432;
    ushort_t* a2h  = P + 67108864;    // 16,777,216 (ec2 out, relu'd)
    ushort_t* a2l  = P + 83886080;    // ends 100,663,296
    ushort_t* a3h  = P;               //  4,194,304 (ec3 out, relu'd)
    ushort_t* a3l  = P + 4194304;
    ushort_t* a4h  = P + 8388608;     //  raw
    ushort_t* a4l  = P + 12582912;
    ushort_t* a4rh = P + 16777216;    //  relu copy
    ushort_t* a4rl = P + 20971520;
    ushort_t* th   = P + 25165824;    //  1,048,576 (res hidden)
    ushort_t* tl   = P + 26214400;
    ushort_t* zh   = P + 27262976;    //  2,097,152
    ushort_t* zl   = P + 29360128;
    ushort_t* qb   = P + 31457280;    //  2,097,152
    ushort_t* d1h  = P + 33554432;    //  4,194,304 (decoder raw)
    ushort_t* d1r  = P + 37748736;    //  relu copy
    ushort_t* t2   = P + 41943040;    //  1,048,576
    ushort_t* u1   = P + 42991616;    //  8,388,608
    ushort_t* u2   = P + 51380224;    // 33,554,432 ends 84,934,656

    // ---- weight arena (fragment-major) ----
    size_t wc = 100663296;
    auto walloc = [&](size_t n) { ushort_t* p = P + wc; wc += n; return p; };
    ushort_t* W_ec2h = walloc(73728);  ushort_t* W_ec2l = walloc(73728);
    ushort_t* W_ec3h = walloc(147456); ushort_t* W_ec3l = walloc(147456);
    ushort_t* W_ec4h = walloc(147456); ushort_t* W_ec4l = walloc(147456);
    ushort_t* W_r0ah = walloc(36864);  ushort_t* W_r0al = walloc(36864);
    ushort_t* W_r0bh = walloc(4096);   ushort_t* W_r0bl = walloc(4096);
    ushort_t* W_r1ah = walloc(36864);  ushort_t* W_r1al = walloc(36864);
    ushort_t* W_r1bh = walloc(4096);   ushort_t* W_r1bl = walloc(4096);
    ushort_t* W_pvqh = walloc(8192);   ushort_t* W_pvql = walloc(8192);
    ushort_t* W_cbh  = walloc(32768);  ushort_t* W_cbl  = walloc(32768);
    ushort_t* W_dc1  = walloc(73728);
    ushort_t* W_d0a  = walloc(36864);
    ushort_t* W_d0b  = walloc(4096);
    ushort_t* W_d1a  = walloc(36864);
    ushort_t* W_d1b  = walloc(4096);
    ushort_t* W_dt1  = walloc(73728);
    ushort_t* W_dt2  = walloc(36864);
    ushort_t* W_dt3  = walloc(9216);

    wc = (wc + 7) & ~(size_t)7;
    float* cn = (float*)(P + wc);               // 512
    float* ls = cn + 512;                       // 1
    unsigned* hist = (unsigned*)(ls + 1);       // 512

    // ---- fused weight prep ----
    PrepTab tab = {}; tab.ne = 17;
    int cum = 0, ei = 0;
    auto addp = [&](const float* src, ushort_t* dh, ushort_t* dl, int O, int I, int T, int mode, int frag) {
        PrepEnt& e = tab.e[ei++];
        e.src = src; e.dh = (long)(dh - P); e.dl = dl ? (long)(dl - P) : -1;
        e.O = O; e.I = I; e.T = T; e.mode = mode; e.frag = frag;
        e.n = frag ? ((O + 15) / 16) * T * (I / 32) * 512 : O * I * T;
        e.blk0 = cum; cum += (e.n + 255) / 256;
    };
    addp(ec2_w, W_ec2h, W_ec2l, 128, 64, 9, 0, 1);
    addp(ec3_w, W_ec3h, W_ec3l, 128, 128, 9, 0, 1);
    addp(ec4_w, W_ec4h, W_ec4l, 128, 128, 9, 0, 1);
    addp(er0a_w, W_r0ah, W_r0al, 32, 128, 9, 0, 1);
    addp(er0b_w, W_r0bh, W_r0bl, 128, 32, 1, 0, 1);
    addp(er1a_w, W_r1ah, W_r1al, 32, 128, 9, 0, 1);
    addp(er1b_w, W_r1bh, W_r1bl, 128, 32, 1, 0, 1);
    addp(pvq_w, W_pvqh, W_pvql, 64, 128, 1, 0, 1);
    addp(cbk, W_cbh, W_cbl, 512, 64, 1, 0, 0);
    addp(dc1_w, W_dc1, nullptr, 128, 64, 9, 0, 1);
    addp(dr0a_w, W_d0a, nullptr, 32, 128, 9, 0, 1);
    addp(dr0b_w, W_d0b, nullptr, 128, 32, 1, 0, 1);
    addp(dr1a_w, W_d1a, nullptr, 32, 128, 9, 0, 1);
    addp(dr1b_w, W_d1b, nullptr, 128, 32, 1, 0, 1);
    addp(dt1_w, W_dt1, nullptr, 64, 128, 9, 1, 1);
    addp(dt2_w, W_dt2, nullptr, 64, 64, 9, 1, 1);
    addp(dt3_w, W_dt3, nullptr, 3, 64, 9, 1, 1);

    hipMemsetAsync(ls, 0, 4 * 513, stream);
    prep_all_k<<<cum, 256, 0, stream>>>(P, tab);
    cnorm_k<<<8, 64, 0, stream>>>(cbk, cn);

    // ---- encoder ----
    ec1_k<<<dim3(64, 4, 32), 256, 0, stream>>>(x, ec1_w, ec1_b, a1h, a1l);
    // template: <MT,MW,NW,S,TT,SPLIT,ADD_RES,RELU_OUT,RELUC,OUT_MODE,MGUARD>
    hconv<4,2,2, 2,0, 1,0,1,0, 0,0><<<dim3(64, 1, 32), 256, 0, stream>>>(       // ec2
        a1h, a1l, W_ec2h, W_ec2l, ec2_b, nullptr, nullptr,
        a2h, a2l, nullptr, nullptr, nullptr, 64, 128, 128, 128, 64, 64);
    hconv<4,2,2, 2,0, 1,0,1,0, 0,0><<<dim3(16, 1, 32), 256, 0, stream>>>(       // ec3
        a2h, a2l, W_ec3h, W_ec3l, ec3_b, nullptr, nullptr,
        a3h, a3l, nullptr, nullptr, nullptr, 128, 64, 64, 128, 32, 32);
    hconv<2,2,2, 1,0, 1,0,0,1, 0,0><<<dim3(16, 2, 32), 256, 0, stream>>>(       // ec4: raw + relu copy
        a3h, a3l, W_ec4h, W_ec4l, ec4_b, nullptr, nullptr,
        a4h, a4l, a4rh, a4rl, nullptr, 128, 32, 32, 128, 32, 32);
    hconv<1,2,2, 1,0, 1,0,1,0, 0,0><<<dim3(16, 1, 32), 256, 0, stream>>>(       // er0a
        a4rh, a4rl, W_r0ah, W_r0al, nullptr, nullptr, nullptr,
        th, tl, nullptr, nullptr, nullptr, 128, 32, 32, 32, 32, 32);
    hconv<2,2,2, 1,1, 1,1,0,1, 0,0><<<dim3(16, 2, 32), 256, 0, stream>>>(       // er0b: +res, raw+relu
        th, tl, W_r0bh, W_r0bl, nullptr, a4h, a4l,
        a4h, a4l, a4rh, a4rl, nullptr, 32, 32, 32, 128, 32, 32);
    hconv<1,2,2, 1,0, 1,0,1,0, 0,0><<<dim3(16, 1, 32), 256, 0, stream>>>(       // er1a
        a4rh, a4rl, W_r1ah, W_r1al, nullptr, nullptr, nullptr,
        th, tl, nullptr, nullptr, nullptr, 128, 32, 32, 32, 32, 32);
    hconv<2,2,2, 1,1, 1,1,1,0, 0,0><<<dim3(16, 2, 32), 256, 0, stream>>>(       // er1b: +res, relu'd
        th, tl, W_r1bh, W_r1bl, nullptr, a4h, a4l,
        a4rh, a4rl, nullptr, nullptr, nullptr, 32, 32, 32, 128, 32, 32);
    hconv<1,2,2, 1,1, 1,0,0,0, 0,0><<<dim3(16, 2, 32), 256, 0, stream>>>(       // pvq 1x1
        a4rh, a4rl, W_pvqh, W_pvql, pvq_b, nullptr, nullptr,
        zh, zl, nullptr, nullptr, nullptr, 128, 32, 32, 64, 32, 32);

    // ---- VQ ----
    vq7_k<<<512, 256, 0, stream>>>(zh, zl, W_cbh, W_cbl, cbk, cn, qb, ls, hist);

    // ---- decoder ----
    hconv<2,2,2, 1,0, 0,0,0,1, 0,0><<<dim3(16, 2, 32), 256, 0, stream>>>(       // dc1: raw + relu copy
        qb, nullptr, W_dc1, nullptr, dc1_b, nullptr, nullptr,
        d1h, nullptr, d1r, nullptr, nullptr, 64, 32, 32, 128, 32, 32);
    hconv<1,2,2, 1,0, 0,0,1,0, 0,0><<<dim3(16, 1, 32), 256, 0, stream>>>(       // dr0a
        d1r, nullptr, W_d0a, nullptr, nullptr, nullptr, nullptr,
        t2, nullptr, nullptr, nullptr, nullptr, 128, 32, 32, 32, 32, 32);
    hconv<2,2,2, 1,1, 0,1,0,1, 0,0><<<dim3(16, 2, 32), 256, 0, stream>>>(       // dr0b
        t2, nullptr, W_d0b, nullptr, nullptr, d1h, nullptr,
        d1h, nullptr, d1r, nullptr, nullptr, 32, 32, 32, 128, 32, 32);
    hconv<1,2,2, 1,0, 0,0,1,0, 0,0><<<dim3(16, 1, 32), 256, 0, stream>>>(       // dr1a
        d1r, nullptr, W_d1a, nullptr, nullptr, nullptr, nullptr,
        t2, nullptr, nullptr, nullptr, nullptr, 128, 32, 32, 32, 32, 32);
    hconv<2,2,2, 1,1, 0,1,1,0, 0,0><<<dim3(16, 2, 32), 256, 0, stream>>>(       // dr1b: relu'd
        t2, nullptr, W_d1b, nullptr, nullptr, d1h, nullptr,
        d1r, nullptr, nullptr, nullptr, nullptr, 32, 32, 32, 128, 32, 32);
    hconv<2,2,2, 1,2, 0,0,1,0, 0,0><<<dim3(16, 1, 32), 256, 0, stream>>>(       // dt1 (convT)
        d1r, nullptr, W_dt1, nullptr, dt1_b, nullptr, nullptr,
        u1, nullptr, nullptr, nullptr, nullptr, 128, 32, 32, 64, 32, 32);
    hconv<2,2,2, 1,2, 0,0,1,0, 0,0><<<dim3(64, 1, 32), 256, 0, stream>>>(       // dt2 (convT)
        u1, nullptr, W_dt2, nullptr, dt2_b, nullptr, nullptr,
        u2, nullptr, nullptr, nullptr, nullptr, 64, 64, 64, 64, 64, 64);
    hconv<1,1,4, 1,2, 0,0,0,0, 1,1><<<dim3(128, 1, 32), 256, 0, stream>>>(      // dt3 -> fp32 NCHW
        u2, nullptr, W_dt3, nullptr, dt3_b, nullptr, nullptr,
        nullptr, nullptr, nullptr, nullptr, out + 1, 64, 128, 128, 3, 128, 128);

    // ---- scalars ----
    fin_k<<<1, 512, 0, stream>>>(hist, ls, out, out_size);
}